// Round 1
// 128.083 us; speedup vs baseline: 1.0283x; 1.0283x over previous
//
#include <hip/hip_runtime.h>
#include <hip/hip_bf16.h>

#define BB 8
#define CC 128
#define HH 64
#define WW 64
#define OO 128
#define NJ 18
#define HW 4096

typedef unsigned short u16;
typedef unsigned int u32;
typedef __attribute__((ext_vector_type(8))) __bf16 bf16x8;
typedef __attribute__((ext_vector_type(4))) float f32x4;

__device__ __forceinline__ u16 f2bf(float f) {
    u32 u = __float_as_uint(f);
    u += 0x7fffu + ((u >> 16) & 1u);   // RNE
    return (u16)(u >> 16);
}
__device__ __forceinline__ float bflo(u32 u) { return __uint_as_float(u << 16); }
__device__ __forceinline__ float bfhi(u32 u) { return __uint_as_float(u & 0xffff0000u); }
__device__ __forceinline__ u32 pk2bf(float s0, float s1) {
    union { __hip_bfloat162 h; u32 u; } cv;
    cv.h = __float22bfloat162_rn(make_float2(s0, s1));   // v_cvt_pk_bf16_f32
    return cv.u;
}

// ---------------------------------------------------------------------------
// k_pre: fused (a) x[b][c][hw] fp32 -> xT[b][hw][c] bf16 transpose and
//        (b) weight prep (wT, wA). Blocks [0,512) do xT, [512,1088) do prep.
//        The two jobs are independent -> merged so they run CONCURRENTLY
//        instead of as two serialized launches.
// ---------------------------------------------------------------------------
__global__ __launch_bounds__(256)
void k_pre(const float* __restrict__ x, u16* __restrict__ xT,
           const float* __restrict__ w_def, const float* __restrict__ w_off,
           u16* __restrict__ wT, u16* __restrict__ wA) {
    __shared__ float tile[64][129];
    const int t = threadIdx.x;
    if (blockIdx.x < 512) {
        const int b = blockIdx.x >> 6;
        const int hw0 = (blockIdx.x & 63) << 6;
        const float* xb = x + (size_t)b * CC * HW + hw0;
        const int tw = t & 63, tc = t >> 6;
#pragma unroll
        for (int r = 0; r < 32; ++r) {
            int c = r * 4 + tc;                 // wave-uniform
            tile[tw][c] = xb[c * HW + tw];
        }
        __syncthreads();
        u16* dst = xT + ((size_t)b * HW + hw0) * CC;
#pragma unroll
        for (int r = 0; r < 4; ++r) {
            int item = t + (r << 8);            // 1024 items = 64 hw x 16 segs
            int seg = item & 15, hw = item >> 4;
            union { u32 d[4]; uint4 v; } p;
#pragma unroll
            for (int i = 0; i < 4; ++i)
                p.d[i] = pk2bf(tile[hw][seg * 8 + 2 * i], tile[hw][seg * 8 + 2 * i + 1]);
            *(uint4*)&dst[hw * CC + seg * 8] = p.v;
        }
    } else {
        int idx = (blockIdx.x - 512) * 256 + t;
        if (idx < 9 * OO * CC) {
            int c = idx & 127, o = (idx >> 7) & 127, kk = idx >> 14;
            wT[idx] = f2bf(w_def[(o * CC + c) * 9 + kk]);
        }
        if (idx < 32 * 1152) {
            int k = idx % 1152, j = idx / 1152;
            int q = k >> 7, c = k & 127;
            wA[idx] = (j < NJ) ? f2bf(w_off[(j * CC + c) * 9 + q]) : (u16)0;
        }
    }
}

// ---------------------------------------------------------------------------
// k_fused: offset conv (was k_off) fused into the sample+GEMM kernel
// (was k_main v7). Each block (b,h) computes its own 18x64 offsets via the
// identical staged-LDS MFMA prolog, writes them to LDS (not global), then
// runs the unchanged register-double-buffered main loop.
//
// Removes: one device-wide barrier (all k_off blocks had to retire before
// any k_main block started), one launch, and the 4.7 MB offs round-trip.
// The 2 co-resident blocks/CU can now overlap one block's offset-MFMA
// phase with the other's gather/interp phase.
//
// LDS is phase-multiplexed in ONE 50,688 B buffer:
//   phase 1: s_x   [198*128] u16 swizzled (bytes 0..50687)
//   phase 2: s_off [18][64]  f32          (bytes 0..4607; s_x is dead)
//   main   : s_samp[2][64*128] u16        (bytes 8192..40959; no alias
//            with s_off, which is only read in the prolog)
// 50.7 KB/block x 2 blocks/CU = 101 KB < 160 KB -> occupancy unchanged.
// ---------------------------------------------------------------------------
__global__ __launch_bounds__(256, 2)
void k_fused(const u16* __restrict__ xT, const u16* __restrict__ wA,
             const float* __restrict__ b_off, const u16* __restrict__ wT,
             const float* __restrict__ b_def, float* __restrict__ out) {
    __shared__ __align__(16) u16 smem[25344];   // 50,688 B multi-phase
    u16*   s_x    = smem;                       // [3 rows x 66 w][128 c] swz
    float* s_off  = (float*)smem;               // [18][64]
    u16*   s_samp = smem + 4096;                // byte offset 8192, [2][8192]

    const int t = threadIdx.x, lane = t & 63, wv = t >> 6;
    const int posl = lane & 15, kg = lane >> 4;
    const int b = blockIdx.x & 7, h = blockIdx.x >> 3;
    const char* xb = (const char*)xT + (size_t)b * (HW * CC * 2);

    // ================= phase 1: offset conv (verbatim k_off) ==============
    for (int it = t; it < 3168; it += 256) {
        int seg = it & 15, pix = it >> 4;       // pix = r*66 + wp
        int r = pix / 66, wp = pix - r * 66;
        int y = h - 1 + r, w = wp - 1;
        uint4 v = make_uint4(0, 0, 0, 0);
        if (y >= 0 && y < HH && w >= 0 && w < WW)
            v = *(const uint4*)&xT[((size_t)(b * HW) + y * WW + w) * CC + seg * 8];
        *(uint4*)&s_x[pix * 128 + ((seg ^ (pix & 15)) * 8)] = v;
    }
    __syncthreads();

    {
        f32x4 acc0 = {0.f, 0.f, 0.f, 0.f}, acc1 = {0.f, 0.f, 0.f, 0.f};
        for (int qq = 0; qq < 9; ++qq) {
            int qy = qq / 3, qx = qq - qy * 3;
            int pix = qy * 66 + (wv * 16 + posl) + qx;
            int prow = pix * 128, pxr = pix & 15;
#pragma unroll
            for (int ki = 0; ki < 4; ++ki) {
                int ks = qq * 4 + ki;
                int cidx = ki * 4 + kg;
                bf16x8 bfr = *(const bf16x8*)&s_x[prow + ((cidx ^ pxr) * 8)];
                bf16x8 a0 = *(const bf16x8*)&wA[posl * 1152 + ks * 32 + kg * 8];
                bf16x8 a1 = *(const bf16x8*)&wA[(16 + posl) * 1152 + ks * 32 + kg * 8];
                acc0 = __builtin_amdgcn_mfma_f32_16x16x32_bf16(a0, bfr, acc0, 0, 0, 0);
                acc1 = __builtin_amdgcn_mfma_f32_16x16x32_bf16(a1, bfr, acc1, 0, 0, 0);
            }
        }
        __syncthreads();   // all s_x reads done before s_off aliases it
        const int pos = wv * 16 + posl;
#pragma unroll
        for (int r = 0; r < 4; ++r) {
            int j = kg * 4 + r;
            s_off[j * 64 + pos] = acc0[r] + b_off[j];
        }
#pragma unroll
        for (int r = 0; r < 4; ++r) {
            int j = 16 + kg * 4 + r;
            if (j < NJ) s_off[j * 64 + pos] = acc1[r] + b_off[j];
        }
    }
    __syncthreads();

    // ================= main: sample + GEMM (k_main v7 body) ===============
    const int gpos = t >> 2;             // 0..63 (= w)
    const int segsub = t & 3;
    const int pxor = gpos & 15;
    const int slotbase = gpos * 128;

    // preload all 18 offset values into registers (now from LDS, not HBM)
    float oyv[9], oxv[9];
#pragma unroll
    for (int kk = 0; kk < 9; ++kk) {
        oyv[kk] = s_off[(2 * kk) * 64 + gpos];
        oxv[kk] = s_off[(2 * kk + 1) * 64 + gpos];
    }

    auto coords = [&](int kk, float oy, float ox, float4& cw, int4& co) {
        int ky = kk / 3, kx = kk - ky * 3;
        float py = (float)(h - 1 + ky) + oy;
        float px = (float)(gpos - 1 + kx) + ox;
        float fy = floorf(py), fx = floorf(px);
        int iy0 = (int)fy, ix0 = (int)fx;
        float wy = py - fy, wx = px - fx;
        int iy1 = iy0 + 1, ix1 = ix0 + 1;
        float my0 = (iy0 >= 0 && iy0 < HH) ? 1.0f : 0.0f;
        float my1 = (iy1 >= 0 && iy1 < HH) ? 1.0f : 0.0f;
        float mx0 = (ix0 >= 0 && ix0 < WW) ? 1.0f : 0.0f;
        float mx1 = (ix1 >= 0 && ix1 < WW) ? 1.0f : 0.0f;
        int iy0c = min(max(iy0, 0), HH - 1), iy1c = min(max(iy1, 0), HH - 1);
        int ix0c = min(max(ix0, 0), WW - 1), ix1c = min(max(ix1, 0), WW - 1);
        float wy1 = 1.0f - wy, wx1 = 1.0f - wx;
        cw = make_float4(my0 * mx0 * wy1 * wx1, my0 * mx1 * wy1 * wx,
                         my1 * mx0 * wy  * wx1, my1 * mx1 * wy  * wx);
        co = make_int4((iy0c * WW + ix0c) << 8, (iy0c * WW + ix1c) << 8,
                       (iy1c * WW + ix0c) << 8, (iy1c * WW + ix1c) << 8);
    };
    auto issue_gather = [&](const int4 co, uint4 q[4][4]) {
#pragma unroll
        for (int j = 0; j < 4; ++j) {
            const int sb = (segsub + 4 * j) * 16;
            q[j][0] = *(const uint4*)(xb + co.x + sb);
            q[j][1] = *(const uint4*)(xb + co.y + sb);
            q[j][2] = *(const uint4*)(xb + co.z + sb);
            q[j][3] = *(const uint4*)(xb + co.w + sb);
        }
    };
    auto interp_store = [&](const float4 cw, uint4 q[4][4], int p) {
#pragma unroll
        for (int j = 0; j < 4; ++j) {
            const int seg = segsub + 4 * j;
            const u32* u00 = (const u32*)&q[j][0];
            const u32* u01 = (const u32*)&q[j][1];
            const u32* u10 = (const u32*)&q[j][2];
            const u32* u11 = (const u32*)&q[j][3];
            union { u32 d[4]; uint4 v; } pk;
#pragma unroll
            for (int i = 0; i < 4; ++i) {
                float s0 = cw.x * bflo(u00[i]) + cw.y * bflo(u01[i])
                         + cw.z * bflo(u10[i]) + cw.w * bflo(u11[i]);
                float s1 = cw.x * bfhi(u00[i]) + cw.y * bfhi(u01[i])
                         + cw.z * bfhi(u10[i]) + cw.w * bfhi(u11[i]);
                pk.d[i] = pk2bf(s0, s1);
            }
            *(uint4*)&s_samp[p * 8192 + slotbase + ((seg ^ pxor) * 8)] = pk.v;
        }
    };
    auto load_w = [&](int kk, bf16x8 wfr[4][2]) {
        const u16* wkk = wT + kk * (OO * CC);
        const int o0 = wv * 32;
#pragma unroll
        for (int ct = 0; ct < 4; ++ct)
#pragma unroll
            for (int nt = 0; nt < 2; ++nt) {
                int o = o0 + nt * 16 + posl;
                wfr[ct][nt] = *(const bf16x8*)&wkk[o * CC + ct * 32 + kg * 8];
            }
    };

    f32x4 acc[4][2];
#pragma unroll
    for (int mt = 0; mt < 4; ++mt) {
        acc[mt][0] = (f32x4){0.f, 0.f, 0.f, 0.f};
        acc[mt][1] = (f32x4){0.f, 0.f, 0.f, 0.f};
    }

    // ---- prolog: weights kk=0, samples kk=0 ----
    bf16x8 wA_[4][2], wB_[4][2];
    float4 cw; int4 co;
    uint4 q[4][4];
    load_w(0, wA_);
    coords(0, oyv[0], oxv[0], cw, co);
    issue_gather(co, q);
    interp_store(cw, q, 0);
    __syncthreads();

#pragma unroll
    for (int kk = 0; kk < 9; ++kk) {
        const int p = kk & 1;

        // ---- issue next kk's weight loads (first!) and gathers ----
        if (kk < 8) {
            load_w(kk + 1, wB_);
            coords(kk + 1, oyv[kk + 1], oxv[kk + 1], cw, co);
            issue_gather(co, q);
        }

        // ---- MFMA phase on samp[p]: weights already in registers ----
#pragma unroll
        for (int ct = 0; ct < 4; ++ct) {
            const int chunk = ct * 4 + kg;
#pragma unroll
            for (int mt = 0; mt < 4; ++mt) {
                bf16x8 afr = *(const bf16x8*)
                    &s_samp[p * 8192 + (mt * 16 + posl) * 128 + ((chunk ^ posl) * 8)];
                acc[mt][0] = __builtin_amdgcn_mfma_f32_16x16x32_bf16(
                    afr, wA_[ct][0], acc[mt][0], 0, 0, 0);
                acc[mt][1] = __builtin_amdgcn_mfma_f32_16x16x32_bf16(
                    afr, wA_[ct][1], acc[mt][1], 0, 0, 0);
            }
        }

        // ---- consume prefetched corners -> samp[p^1]; single barrier ----
        if (kk < 8) {
            interp_store(cw, q, p ^ 1);
            __syncthreads();
        }

        // rotate weight buffers (renamed away by full unroll)
#pragma unroll
        for (int ct = 0; ct < 4; ++ct) {
            wA_[ct][0] = wB_[ct][0];
            wA_[ct][1] = wB_[ct][1];
        }
    }

    // ---- epilogue: D row = pos = mt*16 + kg*4 + r, col = o ----
#pragma unroll
    for (int nt = 0; nt < 2; ++nt) {
        const int o = wv * 32 + nt * 16 + posl;
        const float bd = b_def[o];
        float* orow = out + ((b * OO + o) * HH + h) * WW;
#pragma unroll
        for (int mt = 0; mt < 4; ++mt) {
            float4 res;
            res.x = acc[mt][nt][0] + bd;
            res.y = acc[mt][nt][1] + bd;
            res.z = acc[mt][nt][2] + bd;
            res.w = acc[mt][nt][3] + bd;
            *(float4*)&orow[mt * 16 + kg * 4] = res;
        }
    }
}

extern "C" void kernel_launch(void* const* d_in, const int* in_sizes, int n_in,
                              void* d_out, int out_size, void* d_ws, size_t ws_size,
                              hipStream_t stream) {
    const float* x     = (const float*)d_in[0];
    const float* w_off = (const float*)d_in[1];
    const float* b_off = (const float*)d_in[2];
    const float* w_def = (const float*)d_in[3];
    const float* b_def = (const float*)d_in[4];
    float* out = (float*)d_out;

    u16* xT = (u16*)d_ws;                        // 8*4096*128 bf16 = 8.39 MB
    u16* wT = xT + (size_t)BB * HW * CC;         // 9*128*128       = 0.29 MB
    u16* wA = wT + 9 * OO * CC;                  // 32*1152         = 0.07 MB

    k_pre  <<<1088, 256, 0, stream>>>(x, xT, w_def, w_off, wT, wA);
    k_fused<<< 512, 256, 0, stream>>>(xT, wA, b_off, wT, b_def, out);
}